// Round 7
// baseline (206.447 us; speedup 1.0000x reference)
//
#include <hip/hip_runtime.h>

// ---------------------------------------------------------------------------
// MHA forward, B=8 S=1024 D=768 H=12 hd=64, fp32 in/out, bf16 MFMA compute.
// cvt3 -> QKV GEMM (8-wave 128x128, BK=32, 2-stage LDS dbuf, unroll-2 K-loop)
// -> flash attn (no-max softmax; S^T C-layout fed DIRECTLY as B-operand of
//    16x16x16 MFMA for O^T = V^T P^T — no P LDS round-trip)
// -> proj GEMM (same dbuf structure, fp32 out).
// Reference applies NO 1/sqrt(hd) scale.
// ---------------------------------------------------------------------------

typedef short bf16x8 __attribute__((ext_vector_type(8)));
typedef short bf16x4 __attribute__((ext_vector_type(4)));
typedef float f32x4  __attribute__((ext_vector_type(4)));

#define MFMA16(a, b, c) __builtin_amdgcn_mfma_f32_16x16x32_bf16((a), (b), (c), 0, 0, 0)

#if __has_builtin(__builtin_amdgcn_mfma_f32_16x16x16bf16_1k)
#define MFMAK16(a, b, c) __builtin_amdgcn_mfma_f32_16x16x16bf16_1k((a), (b), (c), 0, 0, 0)
#elif __has_builtin(__builtin_amdgcn_mfma_f32_16x16x16_bf16)
#define MFMAK16(a, b, c) __builtin_amdgcn_mfma_f32_16x16x16_bf16((a), (b), (c), 0, 0, 0)
#else
static __device__ __forceinline__ f32x4 mfmak16_asm(bf16x4 a, bf16x4 b, f32x4 c) {
    asm volatile("v_mfma_f32_16x16x16_bf16 %0, %1, %2, %0" : "+v"(c) : "v"(a), "v"(b));
    return c;
}
#define MFMAK16(a, b, c) mfmak16_asm((a), (b), (c))
#endif

__device__ __forceinline__ unsigned short f2bf(float f) {
    union { float f; unsigned int u; } v; v.f = f;
    unsigned int u = v.u;
    return (unsigned short)((u + 0x7fffu + ((u >> 16) & 1u)) >> 16);  // RTNE
}

__device__ __forceinline__ unsigned int cvt2(float x, float y) {
#if __has_builtin(__builtin_amdgcn_cvt_pk_bf16_f32)
    auto v = __builtin_amdgcn_cvt_pk_bf16_f32(x, y);
    unsigned int b; __builtin_memcpy(&b, &v, 4); return b;
#else
    return (unsigned int)f2bf(x) | ((unsigned int)f2bf(y) << 16);
#endif
}

__device__ __forceinline__ void gl2lds16(const unsigned short* g, unsigned short* l) {
    __builtin_amdgcn_global_load_lds(
        (const unsigned int __attribute__((address_space(1)))*)g,
        (unsigned int __attribute__((address_space(3)))*)l,
        16, 0, 0);
}

// ---------------------------------------------------------------------------
// fused fp32->bf16 convert for x, w_qkv, w_proj (grid exactly 8448*256 float4s)
__global__ void cvt3_kernel(const float* __restrict__ x,
                            const float* __restrict__ wq,
                            const float* __restrict__ wp,
                            unsigned short* __restrict__ xb,
                            unsigned short* __restrict__ wqb,
                            unsigned short* __restrict__ wpb) {
    int i = blockIdx.x * 256 + threadIdx.x;
    const float* s; unsigned short* d; int off;
    if (i < 1572864)      { s = x;  d = xb;  off = i; }
    else if (i < 2015232) { s = wq; d = wqb; off = i - 1572864; }
    else                  { s = wp; d = wpb; off = i - 2015232; }
    float4 v = ((const float4*)s)[off];
    ushort4 o;
    o.x = f2bf(v.x); o.y = f2bf(v.y); o.z = f2bf(v.z); o.w = f2bf(v.w);
    ((ushort4*)d)[off] = o;
}

// ---------------------------------------------------------------------------
// GEMM1: C[8192,2304] = Xbf[8192,768] * Wqkv[2304,768]^T + bias.
// 512 thr = 8 waves, 128x128 tile, BK=32, double-buffered LDS (unroll-2).
// blockIdx.y 0-5 -> Q [B,S,768] (scaled log2e), 6-11 -> K, 12-17 -> V^T.
__global__ __launch_bounds__(512, 4) void gemm_qkv(
    const unsigned short* __restrict__ A,   // [8192][768]
    const unsigned short* __restrict__ Bm,  // [2304][768]
    const float* __restrict__ bias,         // [2304]
    unsigned short* __restrict__ Qo,        // [B,S,768]
    unsigned short* __restrict__ Ko,        // [B,S,768]
    unsigned short* __restrict__ Vto) {     // [B,H,64,S]
    const int K = 768;
    __shared__ __align__(16) unsigned short smem[16384];  // A0|A1|B0|B1; V-epi reuses
    unsigned short* const As0 = smem;
    unsigned short* const As1 = smem + 4096;
    unsigned short* const Bs0 = smem + 8192;
    unsigned short* const Bs1 = smem + 12288;
    const int tid = threadIdx.x;
    const int wave = tid >> 6, lane = tid & 63;
    const int quad = lane >> 4, l16 = lane & 15;
    const int wm = (wave >> 1) * 32, wn = (wave & 1) * 64;
    const int tileM = blockIdx.x * 128, tileN = blockIdx.y * 128;

    f32x4 zero4 = {0.f, 0.f, 0.f, 0.f};
    f32x4 acc[2][4];
#pragma unroll
    for (int i = 0; i < 2; ++i)
#pragma unroll
        for (int j = 0; j < 4; ++j) acc[i][j] = zero4;

    const int sr = tid >> 2, sc = tid & 3;
    const unsigned short* Ag = A + (size_t)(tileM + sr) * K + sc * 8;
    const unsigned short* Bg = Bm + (size_t)(tileN + sr) * K + sc * 8;
    const int sdst = wave << 9;  // shorts

    auto compute = [&](const unsigned short* Ar, const unsigned short* Br) {
        bf16x8 af[2], bfr[4];
#pragma unroll
        for (int t = 0; t < 2; ++t)
            af[t] = *(const bf16x8*)(Ar + (wm + t * 16 + l16) * 32 + quad * 8);
#pragma unroll
        for (int t = 0; t < 4; ++t)
            bfr[t] = *(const bf16x8*)(Br + (wn + t * 16 + l16) * 32 + quad * 8);
#pragma unroll
        for (int tm = 0; tm < 2; ++tm)
#pragma unroll
            for (int tn = 0; tn < 4; ++tn)
                acc[tm][tn] = MFMA16(af[tm], bfr[tn], acc[tm][tn]);
    };

    gl2lds16(Ag, As0 + sdst);
    gl2lds16(Bg, Bs0 + sdst);
    for (int it = 0; it < 24; it += 2) {
        __syncthreads();
        {
            int k1 = (it + 1) << 5;
            gl2lds16(Ag + k1, As1 + sdst);
            gl2lds16(Bg + k1, Bs1 + sdst);
        }
        compute(As0, Bs0);
        __syncthreads();
        if (it + 2 < 24) {
            int k2 = (it + 2) << 5;
            gl2lds16(Ag + k2, As0 + sdst);
            gl2lds16(Bg + k2, Bs0 + sdst);
        }
        compute(As1, Bs1);
    }

    const int t = blockIdx.y / 6;  // 0=Q 1=K 2=V (tile never straddles)
    if (t < 2) {
        const float scale = (t == 0) ? 1.44269504f : 1.0f;  // fold log2e into Q
        unsigned short* dst = (t == 0) ? Qo : Ko;
        const int nb = tileN - t * 768 + wn;
#pragma unroll
        for (int tm = 0; tm < 2; ++tm) {
#pragma unroll
            for (int tn = 0; tn < 4; ++tn) {
                int nl = nb + tn * 16 + l16;
                float bv = bias[tileN + wn + tn * 16 + l16];
#pragma unroll
                for (int r = 0; r < 4; ++r) {
                    int m = tileM + wm + tm * 16 + quad * 4 + r;
                    dst[(size_t)m * 768 + nl] = f2bf((acc[tm][tn][r] + bv) * scale);
                }
            }
        }
    } else {
        // V: stage [64 d][128 s] half in LDS (stride 136 shorts), store coalesced
        const int b = tileM >> 10, srow = tileM & 1023;
#pragma unroll
        for (int h2 = 0; h2 < 2; ++h2) {
            __syncthreads();
            if ((wave & 1) == h2) {
#pragma unroll
                for (int tn = 0; tn < 4; ++tn) {
                    int dl = tn * 16 + l16;
                    float bv = bias[tileN + h2 * 64 + dl];
#pragma unroll
                    for (int tm = 0; tm < 2; ++tm) {
                        int mb = wm + tm * 16 + quad * 4;
                        uint2 pk;
                        pk.x = cvt2(acc[tm][tn][0] + bv, acc[tm][tn][1] + bv);
                        pk.y = cvt2(acc[tm][tn][2] + bv, acc[tm][tn][3] + bv);
                        *(uint2*)(smem + dl * 136 + mb) = pk;
                    }
                }
            }
            __syncthreads();
#pragma unroll
            for (int pass = 0; pass < 2; ++pass) {
                int dl = pass * 32 + (tid >> 4), soff = (tid & 15) * 8;
                bf16x8 row = *(const bf16x8*)(smem + dl * 136 + soff);
                int rem = tileN + h2 * 64 + dl - 1536;
                int h = rem >> 6, d = rem & 63;
                *(bf16x8*)(Vto + (((size_t)b * 12 + h) * 64 + d) * 1024 + srow + soff) = row;
            }
        }
    }
}

// ---------------------------------------------------------------------------
// Flash attention, register-only P path.
// S^T = K·Q^T (16x16x32). Its C-layout (lane: kv=quad*4+r, q=l16) IS the
// B-operand layout of 16x16x16 MFMA, so O^T = V^T·P^T consumes exp(S^T)
// straight from registers. O^T C-layout: lane holds O^T[d=quad*4+r][q=l16].
// LDS: K dbuf 16KB | V dbuf 16KB; Q prologue borrows the K region.
__global__ __launch_bounds__(256) void attn_kernel(
    const unsigned short* __restrict__ Q,
    const unsigned short* __restrict__ Kg,
    const unsigned short* __restrict__ Vt,
    unsigned short* __restrict__ O) {       // [B,S,768] bf16
    __shared__ __align__(16) unsigned short smem[16384];  // 32 KB

    const int tid = threadIdx.x;
    const int wave = tid >> 6, lane = tid & 63;
    const int quad = lane >> 4, l16 = lane & 15;
    const int qt = blockIdx.x;
    const int bh = blockIdx.y;
    const int b = bh / 12, h = bh - b * 12;

    const unsigned short* Qb = Q  + ((size_t)b * 1024 + qt * 128) * 768 + h * 64;
    const unsigned short* Kb = Kg + (size_t)b * 1024 * 768 + h * 64;
    const unsigned short* Vb = Vt + (size_t)bh * 64 * 1024;

    // K buf: smem + buf*4096 (64 kv rows x 64 d, d split in 32-col halves)
    // V buf: smem + 8192 + buf*4096 (64 d rows x 64 kv, kv split halves)
    auto stageKV = [&](int kv0, int buf) {
        int r = tid >> 2, c = tid & 3;
        const unsigned short* gk = Kb + (size_t)(kv0 + r) * 768 + c * 8;
        const unsigned short* gv = Vb + (size_t)r * 1024 + kv0 + c * 8;
        unsigned short* Kd = smem + buf * 4096;
        unsigned short* Vd = smem + 8192 + buf * 4096;
        int dst = (wave << 6) * 8;
        gl2lds16(gk,      Kd + dst);
        gl2lds16(gk + 32, Kd + 2048 + dst);
        gl2lds16(gv,      Vd + dst);
        gl2lds16(gv + 32, Vd + 2048 + dst);
    };

    // prologue: stage Q tile (128x64, stride 768) into the K region (8192 sh)
#pragma unroll
    for (int i = 0; i < 2; ++i) {
        int s = tid + (i << 8);
        int r = s >> 2, c = s & 3;
        const unsigned short* gq = Qb + (size_t)r * 768 + c * 8;
        int dst = ((wave << 6) + (i << 8)) * 8;
        gl2lds16(gq,      smem + dst);         // d-cols 0..31
        gl2lds16(gq + 32, smem + 4096 + dst);  // d-cols 32..63
    }
    __syncthreads();
    bf16x8 qf[2][2];  // [d-half][q-tile]: B-operand of QK (k=d, n=q)
#pragma unroll
    for (int ks = 0; ks < 2; ++ks)
#pragma unroll
        for (int tq = 0; tq < 2; ++tq)
            qf[ks][tq] = *(const bf16x8*)(smem + ks * 4096 +
                                          (wave * 32 + tq * 16 + l16) * 32 + quad * 8);
    __syncthreads();  // all Q reads done before K0 overwrites the region
    stageKV(0, 0);

    f32x4 zero4 = {0.f, 0.f, 0.f, 0.f};
    f32x4 ot[2][4];   // O^T acc: [q-tile][d-tile], lane: d=quad*4+r, q=l16
    float rsum[2] = {0.f, 0.f};
#pragma unroll
    for (int tq = 0; tq < 2; ++tq)
#pragma unroll
        for (int dt = 0; dt < 4; ++dt) ot[tq][dt] = zero4;

    for (int it = 0; it < 16; ++it) {
        __syncthreads();                       // drains stage(it)
        if (it + 1 < 16) stageKV((it + 1) << 6, (it + 1) & 1);
        const unsigned short* Kr = smem + (it & 1) * 4096;
        const unsigned short* Vr = smem + 8192 + (it & 1) * 4096;

        // S^T tiles: lane holds S^T[kv=quad*4+r][q=l16], kv-tile tk
        f32x4 st[4][2];
#pragma unroll
        for (int tk = 0; tk < 4; ++tk)
#pragma unroll
            for (int tq = 0; tq < 2; ++tq) st[tk][tq] = zero4;
#pragma unroll
        for (int ks = 0; ks < 2; ++ks) {
            bf16x8 kf[4];
#pragma unroll
            for (int tk = 0; tk < 4; ++tk)
                kf[tk] = *(const bf16x8*)(Kr + ks * 2048 + (tk * 16 + l16) * 32 + quad * 8);
#pragma unroll
            for (int tk = 0; tk < 4; ++tk)
#pragma unroll
                for (int tq = 0; tq < 2; ++tq)
                    st[tk][tq] = MFMA16(kf[tk], qf[ks][tq], st[tk][tq]);
        }

        // P^T = exp2(S^T) packed to bf16 B-frags in registers; row sums in VALU
        bf16x4 pb[4][2];
#pragma unroll
        for (int tk = 0; tk < 4; ++tk)
#pragma unroll
            for (int tq = 0; tq < 2; ++tq) {
                float e0 = __builtin_amdgcn_exp2f(st[tk][tq][0]);
                float e1 = __builtin_amdgcn_exp2f(st[tk][tq][1]);
                float e2 = __builtin_amdgcn_exp2f(st[tk][tq][2]);
                float e3 = __builtin_amdgcn_exp2f(st[tk][tq][3]);
                rsum[tq] += (e0 + e1) + (e2 + e3);
                union { unsigned int u[2]; bf16x4 v; } uu;
                uu.u[0] = cvt2(e0, e1);
                uu.u[1] = cvt2(e2, e3);
                pb[tk][tq] = uu.v;
            }

        // O^T += V^T(A) * P^T(B) via 16x16x16 MFMA — no LDS round-trip
#pragma unroll
        for (int tk = 0; tk < 4; ++tk) {
            bf16x4 va[4];
#pragma unroll
            for (int dt = 0; dt < 4; ++dt)
                va[dt] = *(const bf16x4*)(Vr + (tk >> 1) * 2048 +
                                          (dt * 16 + l16) * 32 + (tk & 1) * 16 + quad * 4);
#pragma unroll
            for (int tq = 0; tq < 2; ++tq)
#pragma unroll
                for (int dt = 0; dt < 4; ++dt)
                    ot[tq][dt] = MFMAK16(va[dt], pb[tk][tq], ot[tq][dt]);
        }
    }

    // rsum: reduce across quads -> every lane gets full sum for its q=l16
#pragma unroll
    for (int tq = 0; tq < 2; ++tq) {
        rsum[tq] += __shfl_xor(rsum[tq], 16, 64);
        rsum[tq] += __shfl_xor(rsum[tq], 32, 64);
    }
    float inv[2] = { 1.0f / rsum[0], 1.0f / rsum[1] };

    // epilogue: O[b, s=q, h*64 + d], lane writes 4 consecutive d per (tq,dt)
#pragma unroll
    for (int tq = 0; tq < 2; ++tq) {
        int srow = qt * 128 + wave * 32 + tq * 16 + l16;
        unsigned short* orow = O + ((size_t)b * 1024 + srow) * 768 + h * 64 + quad * 4;
#pragma unroll
        for (int dt = 0; dt < 4; ++dt) {
            uint2 pk;
            pk.x = cvt2(ot[tq][dt][0] * inv[tq], ot[tq][dt][1] * inv[tq]);
            pk.y = cvt2(ot[tq][dt][2] * inv[tq], ot[tq][dt][3] * inv[tq]);
            *(uint2*)(orow + dt * 16) = pk;
        }
    }
}

// ---------------------------------------------------------------------------
// GEMM3: out[8192,768] = Obf[8192,768] * Wproj[768,768]^T + bias, fp32 out.
__global__ __launch_bounds__(512, 4) void gemm_proj(
    const unsigned short* __restrict__ A,
    const unsigned short* __restrict__ Bm,
    const float* __restrict__ bias,
    float* __restrict__ out) {
    const int K = 768;
    __shared__ __align__(16) unsigned short smem[16384];
    unsigned short* const As0 = smem;
    unsigned short* const As1 = smem + 4096;
    unsigned short* const Bs0 = smem + 8192;
    unsigned short* const Bs1 = smem + 12288;
    const int tid = threadIdx.x;
    const int wave = tid >> 6, lane = tid & 63;
    const int quad = lane >> 4, l16 = lane & 15;
    const int wm = (wave >> 1) * 32, wn = (wave & 1) * 64;
    const int tileM = blockIdx.x * 128, tileN = blockIdx.y * 128;

    f32x4 zero4 = {0.f, 0.f, 0.f, 0.f};
    f32x4 acc[2][4];
#pragma unroll
    for (int i = 0; i < 2; ++i)
#pragma unroll
        for (int j = 0; j < 4; ++j) acc[i][j] = zero4;

    const int sr = tid >> 2, sc = tid & 3;
    const unsigned short* Ag = A + (size_t)(tileM + sr) * K + sc * 8;
    const unsigned short* Bg = Bm + (size_t)(tileN + sr) * K + sc * 8;
    const int sdst = wave << 9;

    auto compute = [&](const unsigned short* Ar, const unsigned short* Br) {
        bf16x8 af[2], bfr[4];
#pragma unroll
        for (int t = 0; t < 2; ++t)
            af[t] = *(const bf16x8*)(Ar + (wm + t * 16 + l16) * 32 + quad * 8);
#pragma unroll
        for (int t = 0; t < 4; ++t)
            bfr[t] = *(const bf16x8*)(Br + (wn + t * 16 + l16) * 32 + quad * 8);
#pragma unroll
        for (int tm = 0; tm < 2; ++tm)
#pragma unroll
            for (int tn = 0; tn < 4; ++tn)
                acc[tm][tn] = MFMA16(af[tm], bfr[tn], acc[tm][tn]);
    };

    gl2lds16(Ag, As0 + sdst);
    gl2lds16(Bg, Bs0 + sdst);
    for (int it = 0; it < 24; it += 2) {
        __syncthreads();
        {
            int k1 = (it + 1) << 5;
            gl2lds16(Ag + k1, As1 + sdst);
            gl2lds16(Bg + k1, Bs1 + sdst);
        }
        compute(As0, Bs0);
        __syncthreads();
        if (it + 2 < 24) {
            int k2 = (it + 2) << 5;
            gl2lds16(Ag + k2, As0 + sdst);
            gl2lds16(Bg + k2, Bs0 + sdst);
        }
        compute(As1, Bs1);
    }

#pragma unroll
    for (int tm = 0; tm < 2; ++tm) {
#pragma unroll
        for (int tn = 0; tn < 4; ++tn) {
            int n = tileN + wn + tn * 16 + l16;
            float bv = bias[n];
#pragma unroll
            for (int r = 0; r < 4; ++r) {
                int m = tileM + wm + tm * 16 + quad * 4 + r;
                out[(size_t)m * 768 + n] = acc[tm][tn][r] + bv;
            }
        }
    }
}

// ---------------------------------------------------------------------------
extern "C" void kernel_launch(void* const* d_in, const int* in_sizes, int n_in,
                              void* d_out, int out_size, void* d_ws, size_t ws_size,
                              hipStream_t stream) {
    (void)in_sizes; (void)n_in; (void)out_size; (void)ws_size;
    const float* x      = (const float*)d_in[0];
    const float* w_qkv  = (const float*)d_in[1];
    const float* b_qkv  = (const float*)d_in[2];
    const float* w_proj = (const float*)d_in[3];
    const float* b_proj = (const float*)d_in[4];
    float* out = (float*)d_out;

    char* ws = (char*)d_ws;
    unsigned short* xb     = (unsigned short*)(ws + 0);         // bf16 X, then attn O
    unsigned short* wqkvb  = (unsigned short*)(ws + 12582912);
    unsigned short* wprojb = (unsigned short*)(ws + 16121856);
    unsigned short* Qw     = (unsigned short*)(ws + 17301504);  // [B,S,768]
    unsigned short* Kw     = (unsigned short*)(ws + 29884416);  // [B,S,768]
    unsigned short* Vtw    = (unsigned short*)(ws + 42467328);  // [B,H,64,S]

    cvt3_kernel<<<8448, 256, 0, stream>>>(x, w_qkv, w_proj, xb, wqkvb, wprojb);
    gemm_qkv<<<dim3(64, 18), 512, 0, stream>>>(xb, wqkvb, b_qkv, Qw, Kw, Vtw);
    attn_kernel<<<dim3(8, 96), 256, 0, stream>>>(Qw, Kw, Vtw, xb);
    gemm_proj<<<dim3(64, 6), 512, 0, stream>>>(xb, wprojb, b_proj, out);
}

// Round 8
// 186.959 us; speedup vs baseline: 1.1042x; 1.1042x over previous
//
#include <hip/hip_runtime.h>

// ---------------------------------------------------------------------------
// MHA forward, B=8 S=1024 D=768 H=12 hd=64, fp32 in/out, bf16 MFMA compute.
// cvt3 -> QKV GEMM (8-wave 128x128, BK=32, 2-stage LDS dbuf, unroll-2 K-loop)
// -> flash attn (no-max softmax, S^T trick, reg Q frags, KV dbuf,
//    XCD-local grid: all q-tiles of one (b,h) on one XCD for L2 KV reuse)
// -> proj GEMM (same dbuf structure, fp32 out).
// Reference applies NO 1/sqrt(hd) scale.
// ---------------------------------------------------------------------------

typedef short bf16x8 __attribute__((ext_vector_type(8)));
typedef float f32x4  __attribute__((ext_vector_type(4)));

#define MFMA16(a, b, c) __builtin_amdgcn_mfma_f32_16x16x32_bf16((a), (b), (c), 0, 0, 0)

__device__ __forceinline__ unsigned short f2bf(float f) {
    union { float f; unsigned int u; } v; v.f = f;
    unsigned int u = v.u;
    return (unsigned short)((u + 0x7fffu + ((u >> 16) & 1u)) >> 16);  // RTNE
}

__device__ __forceinline__ unsigned int cvt2(float x, float y) {
#if __has_builtin(__builtin_amdgcn_cvt_pk_bf16_f32)
    auto v = __builtin_amdgcn_cvt_pk_bf16_f32(x, y);
    unsigned int b; __builtin_memcpy(&b, &v, 4); return b;
#else
    return (unsigned int)f2bf(x) | ((unsigned int)f2bf(y) << 16);
#endif
}

__device__ __forceinline__ void gl2lds16(const unsigned short* g, unsigned short* l) {
    __builtin_amdgcn_global_load_lds(
        (const unsigned int __attribute__((address_space(1)))*)g,
        (unsigned int __attribute__((address_space(3)))*)l,
        16, 0, 0);
}

// ---------------------------------------------------------------------------
// fused fp32->bf16 convert for x, w_qkv, w_proj (grid exactly 8448*256 float4s)
__global__ void cvt3_kernel(const float* __restrict__ x,
                            const float* __restrict__ wq,
                            const float* __restrict__ wp,
                            unsigned short* __restrict__ xb,
                            unsigned short* __restrict__ wqb,
                            unsigned short* __restrict__ wpb) {
    int i = blockIdx.x * 256 + threadIdx.x;
    const float* s; unsigned short* d; int off;
    if (i < 1572864)      { s = x;  d = xb;  off = i; }
    else if (i < 2015232) { s = wq; d = wqb; off = i - 1572864; }
    else                  { s = wp; d = wpb; off = i - 2015232; }
    float4 v = ((const float4*)s)[off];
    ushort4 o;
    o.x = f2bf(v.x); o.y = f2bf(v.y); o.z = f2bf(v.z); o.w = f2bf(v.w);
    ((ushort4*)d)[off] = o;
}

// ---------------------------------------------------------------------------
// GEMM1: C[8192,2304] = Xbf[8192,768] * Wqkv[2304,768]^T + bias.
// 512 thr = 8 waves, 128x128 tile, BK=32, double-buffered LDS (unroll-2).
// blockIdx.y 0-5 -> Q [B,S,768] (scaled log2e), 6-11 -> K, 12-17 -> V^T.
__global__ __launch_bounds__(512, 4) void gemm_qkv(
    const unsigned short* __restrict__ A,   // [8192][768]
    const unsigned short* __restrict__ Bm,  // [2304][768]
    const float* __restrict__ bias,         // [2304]
    unsigned short* __restrict__ Qo,        // [B,S,768]
    unsigned short* __restrict__ Ko,        // [B,S,768]
    unsigned short* __restrict__ Vto) {     // [B,H,64,S]
    const int K = 768;
    __shared__ __align__(16) unsigned short smem[16384];  // A0|A1|B0|B1; V-epi reuses
    unsigned short* const As0 = smem;
    unsigned short* const As1 = smem + 4096;
    unsigned short* const Bs0 = smem + 8192;
    unsigned short* const Bs1 = smem + 12288;
    const int tid = threadIdx.x;
    const int wave = tid >> 6, lane = tid & 63;
    const int quad = lane >> 4, l16 = lane & 15;
    const int wm = (wave >> 1) * 32, wn = (wave & 1) * 64;
    const int tileM = blockIdx.x * 128, tileN = blockIdx.y * 128;

    f32x4 zero4 = {0.f, 0.f, 0.f, 0.f};
    f32x4 acc[2][4];
#pragma unroll
    for (int i = 0; i < 2; ++i)
#pragma unroll
        for (int j = 0; j < 4; ++j) acc[i][j] = zero4;

    const int sr = tid >> 2, sc = tid & 3;
    const unsigned short* Ag = A + (size_t)(tileM + sr) * K + sc * 8;
    const unsigned short* Bg = Bm + (size_t)(tileN + sr) * K + sc * 8;
    const int sdst = wave << 9;  // shorts

    auto compute = [&](const unsigned short* Ar, const unsigned short* Br) {
        bf16x8 af[2], bfr[4];
#pragma unroll
        for (int t = 0; t < 2; ++t)
            af[t] = *(const bf16x8*)(Ar + (wm + t * 16 + l16) * 32 + quad * 8);
#pragma unroll
        for (int t = 0; t < 4; ++t)
            bfr[t] = *(const bf16x8*)(Br + (wn + t * 16 + l16) * 32 + quad * 8);
#pragma unroll
        for (int tm = 0; tm < 2; ++tm)
#pragma unroll
            for (int tn = 0; tn < 4; ++tn)
                acc[tm][tn] = MFMA16(af[tm], bfr[tn], acc[tm][tn]);
    };

    gl2lds16(Ag, As0 + sdst);
    gl2lds16(Bg, Bs0 + sdst);
    for (int it = 0; it < 24; it += 2) {
        __syncthreads();
        {
            int k1 = (it + 1) << 5;
            gl2lds16(Ag + k1, As1 + sdst);
            gl2lds16(Bg + k1, Bs1 + sdst);
        }
        compute(As0, Bs0);
        __syncthreads();
        if (it + 2 < 24) {
            int k2 = (it + 2) << 5;
            gl2lds16(Ag + k2, As0 + sdst);
            gl2lds16(Bg + k2, Bs0 + sdst);
        }
        compute(As1, Bs1);
    }

    const int t = blockIdx.y / 6;  // 0=Q 1=K 2=V (tile never straddles)
    if (t < 2) {
        const float scale = (t == 0) ? 1.44269504f : 1.0f;  // fold log2e into Q
        unsigned short* dst = (t == 0) ? Qo : Ko;
        const int nb = tileN - t * 768 + wn;
#pragma unroll
        for (int tm = 0; tm < 2; ++tm) {
#pragma unroll
            for (int tn = 0; tn < 4; ++tn) {
                int nl = nb + tn * 16 + l16;
                float bv = bias[tileN + wn + tn * 16 + l16];
#pragma unroll
                for (int r = 0; r < 4; ++r) {
                    int m = tileM + wm + tm * 16 + quad * 4 + r;
                    dst[(size_t)m * 768 + nl] = f2bf((acc[tm][tn][r] + bv) * scale);
                }
            }
        }
    } else {
        // V: stage [64 d][128 s] half in LDS (stride 136 shorts), store coalesced
        const int b = tileM >> 10, srow = tileM & 1023;
#pragma unroll
        for (int h2 = 0; h2 < 2; ++h2) {
            __syncthreads();
            if ((wave & 1) == h2) {
#pragma unroll
                for (int tn = 0; tn < 4; ++tn) {
                    int dl = tn * 16 + l16;
                    float bv = bias[tileN + h2 * 64 + dl];
#pragma unroll
                    for (int tm = 0; tm < 2; ++tm) {
                        int mb = wm + tm * 16 + quad * 4;
                        uint2 pk;
                        pk.x = cvt2(acc[tm][tn][0] + bv, acc[tm][tn][1] + bv);
                        pk.y = cvt2(acc[tm][tn][2] + bv, acc[tm][tn][3] + bv);
                        *(uint2*)(smem + dl * 136 + mb) = pk;
                    }
                }
            }
            __syncthreads();
#pragma unroll
            for (int pass = 0; pass < 2; ++pass) {
                int dl = pass * 32 + (tid >> 4), soff = (tid & 15) * 8;
                bf16x8 row = *(const bf16x8*)(smem + dl * 136 + soff);
                int rem = tileN + h2 * 64 + dl - 1536;
                int h = rem >> 6, d = rem & 63;
                *(bf16x8*)(Vto + (((size_t)b * 12 + h) * 64 + d) * 1024 + srow + soff) = row;
            }
        }
    }
}

// ---------------------------------------------------------------------------
// Flash attention (round-6 structure). Q,K in [B,S,768], V^T in [B,H,64,S].
// Q frags register-resident; Ps overlays Q-staging region; K/V double-buffered.
// Grid is (bh, qt) = (96, 8): linear id = qt*96+bh -> XCD = bh%8, so all 8
// q-tiles of one (b,h) share an XCD and its L2 serves the KV re-reads.
__global__ __launch_bounds__(256) void attn_kernel(
    const unsigned short* __restrict__ Q,
    const unsigned short* __restrict__ Kg,
    const unsigned short* __restrict__ Vt,
    unsigned short* __restrict__ O) {       // [B,S,768] bf16
    __shared__ __align__(16) unsigned short smem[24576];  // 48 KB
    unsigned short* Ps = smem;              // 128*64 shorts (Q halves in prologue)

    const int tid = threadIdx.x;
    const int wave = tid >> 6, lane = tid & 63;
    const int quad = lane >> 4, l16 = lane & 15;
    const int s4 = l16 & 3;                  // Ps swizzle key
    const int bh = blockIdx.x;               // 0..95  (XCD = bh % 8)
    const int qt = blockIdx.y;               // 0..7
    const int b = bh / 12, h = bh - b * 12;

    const unsigned short* Qb = Q  + ((size_t)b * 1024 + qt * 128) * 768 + h * 64;
    const unsigned short* Kb = Kg + (size_t)b * 1024 * 768 + h * 64;
    const unsigned short* Vb = Vt + (size_t)bh * 64 * 1024;

    auto stageKV = [&](int kv0, int buf) {
        int r = tid >> 2, c = tid & 3;
        const unsigned short* gk = Kb + (size_t)(kv0 + r) * 768 + c * 8;
        const unsigned short* gv = Vb + (size_t)r * 1024 + kv0 + c * 8;
        unsigned short* Kd = smem + 8192 + buf * 4096;
        unsigned short* Vd = smem + 16384 + buf * 4096;
        int dst = (wave << 6) * 8;
        gl2lds16(gk,      Kd + dst);
        gl2lds16(gk + 32, Kd + 2048 + dst);
        gl2lds16(gv,      Vd + dst);
        gl2lds16(gv + 32, Vd + 2048 + dst);
    };

    // stage Q tile (128x64, row stride 768) into Ps region, split 32-col halves
#pragma unroll
    for (int i = 0; i < 2; ++i) {
        int s = tid + (i << 8);
        int r = s >> 2, c = s & 3;
        const unsigned short* gq = Qb + (size_t)r * 768 + c * 8;
        int dst = ((wave << 6) + (i << 8)) * 8;
        gl2lds16(gq,      smem + dst);
        gl2lds16(gq + 32, smem + 4096 + dst);
    }
    stageKV(0, 0);
    __syncthreads();  // Q + KV0 ready
    bf16x8 qf[2][2];
#pragma unroll
    for (int ks = 0; ks < 2; ++ks)
#pragma unroll
        for (int tq = 0; tq < 2; ++tq)
            qf[ks][tq] = *(const bf16x8*)(smem + ks * 4096 +
                                          (wave * 32 + tq * 16 + l16) * 32 + quad * 8);
    __syncthreads();  // Q reads done; Ps region writable

    f32x4 zero4 = {0.f, 0.f, 0.f, 0.f};
    f32x4 oacc[2][4];
    float rsum[2] = {0.f, 0.f};
#pragma unroll
    for (int tm = 0; tm < 2; ++tm)
#pragma unroll
        for (int tv = 0; tv < 4; ++tv) oacc[tm][tv] = zero4;

    for (int it = 0; it < 16; ++it) {
        if (it + 1 < 16) stageKV((it + 1) << 6, (it + 1) & 1);
        const unsigned short* Kr = smem + 8192 + (it & 1) * 4096;
        const unsigned short* Vr = smem + 16384 + (it & 1) * 4096;

        // S^T tiles: D[k=quad*4+r][qrow=l16] = MFMA(Kfrag, Qfrag)
        f32x4 st[4][2];
#pragma unroll
        for (int tk = 0; tk < 4; ++tk)
#pragma unroll
            for (int tq = 0; tq < 2; ++tq) st[tk][tq] = zero4;
#pragma unroll
        for (int ks = 0; ks < 2; ++ks) {
            bf16x8 kf[4];
#pragma unroll
            for (int tk = 0; tk < 4; ++tk)
                kf[tk] = *(const bf16x8*)(Kr + ks * 2048 + (tk * 16 + l16) * 32 + quad * 8);
#pragma unroll
            for (int tk = 0; tk < 4; ++tk)
#pragma unroll
                for (int tq = 0; tq < 2; ++tq)
                    st[tk][tq] = MFMA16(kf[tk], qf[ks][tq], st[tk][tq]);
        }

        // P = exp2(S^T), packed b64 writes (swizzled); per-lane row-sum accum
#pragma unroll
        for (int tq = 0; tq < 2; ++tq) {
            unsigned short* prp = Ps + (wave * 32 + tq * 16 + l16) * 64 + quad * 4;
#pragma unroll
            for (int tk = 0; tk < 4; ++tk) {
                float e0 = __builtin_amdgcn_exp2f(st[tk][tq][0]);
                float e1 = __builtin_amdgcn_exp2f(st[tk][tq][1]);
                float e2 = __builtin_amdgcn_exp2f(st[tk][tq][2]);
                float e3 = __builtin_amdgcn_exp2f(st[tk][tq][3]);
                rsum[tq] += (e0 + e1) + (e2 + e3);
                uint2 pk;
                pk.x = cvt2(e0, e1);
                pk.y = cvt2(e2, e3);
                *(uint2*)(prp + ((tk ^ s4) << 4)) = pk;
            }
        }

        // O += P*V   (same-wave Ps strip; in-order LDS pipe, no barrier)
#pragma unroll
        for (int ks2 = 0; ks2 < 2; ++ks2) {
            bf16x8 ap[2], bv[4];
            int colswz = ((ks2 << 5) + (quad << 3)) ^ (s4 << 4);
#pragma unroll
            for (int tm = 0; tm < 2; ++tm)
                ap[tm] = *(const bf16x8*)(Ps + (wave * 32 + tm * 16 + l16) * 64 + colswz);
#pragma unroll
            for (int tv = 0; tv < 4; ++tv)
                bv[tv] = *(const bf16x8*)(Vr + ks2 * 2048 + (tv * 16 + l16) * 32 + quad * 8);
#pragma unroll
            for (int tm = 0; tm < 2; ++tm)
#pragma unroll
                for (int tv = 0; tv < 4; ++tv)
                    oacc[tm][tv] = MFMA16(ap[tm], bv[tv], oacc[tm][tv]);
        }
        __syncthreads();  // next tile ready; this buf's readers done
    }

    // finish row sums: reduce across quads (lanes sharing l16), redistribute
#pragma unroll
    for (int tq = 0; tq < 2; ++tq) {
        rsum[tq] += __shfl_xor(rsum[tq], 16, 64);
        rsum[tq] += __shfl_xor(rsum[tq], 32, 64);
    }
    float* sums = (float*)smem;  // 128 floats; Ps dead
    if (quad == 0) {
        sums[wave * 32 + l16]      = rsum[0];
        sums[wave * 32 + 16 + l16] = rsum[1];
    }
    __syncthreads();

#pragma unroll
    for (int tm = 0; tm < 2; ++tm) {
        f32x4 inv;
#pragma unroll
        for (int r = 0; r < 4; ++r)
            inv[r] = 1.0f / sums[wave * 32 + tm * 16 + quad * 4 + r];
#pragma unroll
        for (int tv = 0; tv < 4; ++tv)
#pragma unroll
            for (int r = 0; r < 4; ++r) {
                int srow = qt * 128 + wave * 32 + tm * 16 + quad * 4 + r;
                int col = h * 64 + tv * 16 + l16;
                O[((size_t)b * 1024 + srow) * 768 + col] = f2bf(oacc[tm][tv][r] * inv[r]);
            }
    }
}

// ---------------------------------------------------------------------------
// GEMM3: out[8192,768] = Obf[8192,768] * Wproj[768,768]^T + bias, fp32 out.
__global__ __launch_bounds__(512, 4) void gemm_proj(
    const unsigned short* __restrict__ A,
    const unsigned short* __restrict__ Bm,
    const float* __restrict__ bias,
    float* __restrict__ out) {
    const int K = 768;
    __shared__ __align__(16) unsigned short smem[16384];
    unsigned short* const As0 = smem;
    unsigned short* const As1 = smem + 4096;
    unsigned short* const Bs0 = smem + 8192;
    unsigned short* const Bs1 = smem + 12288;
    const int tid = threadIdx.x;
    const int wave = tid >> 6, lane = tid & 63;
    const int quad = lane >> 4, l16 = lane & 15;
    const int wm = (wave >> 1) * 32, wn = (wave & 1) * 64;
    const int tileM = blockIdx.x * 128, tileN = blockIdx.y * 128;

    f32x4 zero4 = {0.f, 0.f, 0.f, 0.f};
    f32x4 acc[2][4];
#pragma unroll
    for (int i = 0; i < 2; ++i)
#pragma unroll
        for (int j = 0; j < 4; ++j) acc[i][j] = zero4;

    const int sr = tid >> 2, sc = tid & 3;
    const unsigned short* Ag = A + (size_t)(tileM + sr) * K + sc * 8;
    const unsigned short* Bg = Bm + (size_t)(tileN + sr) * K + sc * 8;
    const int sdst = wave << 9;

    auto compute = [&](const unsigned short* Ar, const unsigned short* Br) {
        bf16x8 af[2], bfr[4];
#pragma unroll
        for (int t = 0; t < 2; ++t)
            af[t] = *(const bf16x8*)(Ar + (wm + t * 16 + l16) * 32 + quad * 8);
#pragma unroll
        for (int t = 0; t < 4; ++t)
            bfr[t] = *(const bf16x8*)(Br + (wn + t * 16 + l16) * 32 + quad * 8);
#pragma unroll
        for (int tm = 0; tm < 2; ++tm)
#pragma unroll
            for (int tn = 0; tn < 4; ++tn)
                acc[tm][tn] = MFMA16(af[tm], bfr[tn], acc[tm][tn]);
    };

    gl2lds16(Ag, As0 + sdst);
    gl2lds16(Bg, Bs0 + sdst);
    for (int it = 0; it < 24; it += 2) {
        __syncthreads();
        {
            int k1 = (it + 1) << 5;
            gl2lds16(Ag + k1, As1 + sdst);
            gl2lds16(Bg + k1, Bs1 + sdst);
        }
        compute(As0, Bs0);
        __syncthreads();
        if (it + 2 < 24) {
            int k2 = (it + 2) << 5;
            gl2lds16(Ag + k2, As0 + sdst);
            gl2lds16(Bg + k2, Bs0 + sdst);
        }
        compute(As1, Bs1);
    }

#pragma unroll
    for (int tm = 0; tm < 2; ++tm) {
#pragma unroll
        for (int tn = 0; tn < 4; ++tn) {
            int n = tileN + wn + tn * 16 + l16;
            float bv = bias[n];
#pragma unroll
            for (int r = 0; r < 4; ++r) {
                int m = tileM + wm + tm * 16 + quad * 4 + r;
                out[(size_t)m * 768 + n] = acc[tm][tn][r] + bv;
            }
        }
    }
}

// ---------------------------------------------------------------------------
extern "C" void kernel_launch(void* const* d_in, const int* in_sizes, int n_in,
                              void* d_out, int out_size, void* d_ws, size_t ws_size,
                              hipStream_t stream) {
    (void)in_sizes; (void)n_in; (void)out_size; (void)ws_size;
    const float* x      = (const float*)d_in[0];
    const float* w_qkv  = (const float*)d_in[1];
    const float* b_qkv  = (const float*)d_in[2];
    const float* w_proj = (const float*)d_in[3];
    const float* b_proj = (const float*)d_in[4];
    float* out = (float*)d_out;

    char* ws = (char*)d_ws;
    unsigned short* xb     = (unsigned short*)(ws + 0);         // bf16 X, then attn O
    unsigned short* wqkvb  = (unsigned short*)(ws + 12582912);
    unsigned short* wprojb = (unsigned short*)(ws + 16121856);
    unsigned short* Qw     = (unsigned short*)(ws + 17301504);  // [B,S,768]
    unsigned short* Kw     = (unsigned short*)(ws + 29884416);  // [B,S,768]
    unsigned short* Vtw    = (unsigned short*)(ws + 42467328);  // [B,H,64,S]

    cvt3_kernel<<<8448, 256, 0, stream>>>(x, w_qkv, w_proj, xb, wqkvb, wprojb);
    gemm_qkv<<<dim3(64, 18), 512, 0, stream>>>(xb, wqkvb, b_qkv, Qw, Kw, Vtw);
    // (96, 8): bh fastest -> XCD = bh % 8; q-tiles of one (b,h) share an XCD/L2
    attn_kernel<<<dim3(96, 8), 256, 0, stream>>>(Qw, Kw, Vtw, xb);
    gemm_proj<<<dim3(64, 6), 512, 0, stream>>>(xb, wprojb, b_proj, out);
}